// Round 1
// baseline (129.864 us; speedup 1.0000x reference)
//
#include <hip/hip_runtime.h>

// Head: x[8,2048,1024] fp32 -> q,k,v = x@w{q,k,v} -> causal softmax(q k^T * sqrt(128)) @ v
// Precision: bf16x3 split-GEMM for projections and QK^T (fp32-grade scores), bf16 PV.

#define NB 8
#define NT 2048
#define NE 1024
#define ND 128
#define NM (NB * NT)  // 16384

typedef unsigned short U16;
typedef unsigned int U32;
typedef __attribute__((ext_vector_type(8))) short vbf8;  // 8 bf16 (4 VGPR) MFMA frag
typedef __attribute__((ext_vector_type(4))) float vf4;   // MFMA 16x16 accum

__device__ __forceinline__ U16 f2bf(float f) {  // RNE fp32->bf16
  U32 u = __builtin_bit_cast(U32, f);
  u += 0x7fffu + ((u >> 16) & 1u);
  return (U16)(u >> 16);
}
__device__ __forceinline__ float bf2f(U16 h) {
  U32 u = ((U32)h) << 16;
  return __builtin_bit_cast(float, u);
}
__device__ __forceinline__ void gl_lds16(const void* g, void* l) {
  // async global->LDS, 16B per lane; LDS dest = wave-uniform base + lane*16
  __builtin_amdgcn_global_load_lds((__attribute__((address_space(1))) void*)g,
                                   (__attribute__((address_space(3))) void*)l, 16, 0, 0);
}

// ---------------- kernel 1: weight transpose + split (fold sqrt(128) into wq) ---------
__global__ void wsplit_kernel(const float* __restrict__ wq, const float* __restrict__ wk,
                              const float* __restrict__ wv, U16* __restrict__ wth,
                              U16* __restrict__ wtl) {
  int id = blockIdx.x * 256 + threadIdx.x;  // [0, 384*1024)
  if (id >= 384 * 1024) return;
  int n = id >> 10, e = id & 1023;
  float v;
  if (n < 128)      v = wq[e * 128 + n] * 11.313708498984761f;  // scores * d^0.5 folded in
  else if (n < 256) v = wk[e * 128 + (n - 128)];
  else              v = wv[e * 128 + (n - 256)];
  U16 h = f2bf(v);
  wth[id] = h;
  wtl[id] = f2bf(v - bf2f(h));
}

// ---------------- kernel 2: QKV projection, bf16x3 split GEMM ------------------------
// A = x [16384][1024] fp32 (reg-staged + split), B = wT [384][1024] hi/lo (BT layout).
// grid (128, 3): blockIdx.y 0->Q(hi/lo) 1->K(hi/lo) 2->V(bf16, transposed [b][128][2048])
__global__ __launch_bounds__(256) void qkv_kernel(
    const float* __restrict__ x, const U16* __restrict__ wth, const U16* __restrict__ wtl,
    U16* __restrict__ qh, U16* __restrict__ ql, U16* __restrict__ kh, U16* __restrict__ kl,
    U16* __restrict__ vt) {
  __shared__ __align__(16) char smem[35840];  // Ah/Al/Bh/Bl [128][32] bf16 (32KB); reuse for V-transpose (34816B)
  U16* Ah = (U16*)smem;
  U16* Al = (U16*)(smem + 8192);
  U16* Bh = (U16*)(smem + 16384);
  U16* Bl = (U16*)(smem + 24576);

  const int tid = threadIdx.x;
  const int w = tid >> 6, lane = tid & 63;
  const int fr = lane & 15, fq = lane >> 4;
  const int m0 = blockIdx.x * 128;
  const int nt = blockIdx.y;
  const U16* bh_src = wth + nt * (128 * 1024);
  const U16* bl_src = wtl + nt * (128 * 1024);

  const vf4 vzero = {0.f, 0.f, 0.f, 0.f};
  vf4 acc[4][4];
#pragma unroll
  for (int i = 0; i < 4; ++i)
#pragma unroll
    for (int j = 0; j < 4; ++j) acc[i][j] = vzero;

  const int wm = (w >> 1) * 64, wn = (w & 1) * 64;
  const int arow = tid >> 1, acol = (tid & 1) * 16;

  for (int k0 = 0; k0 < 1024; k0 += 32) {
    // async-stage B hi/lo tiles [128 n][32 k]
#pragma unroll
    for (int p = 0; p < 2; ++p) {
      const int g = p * 256 + tid;
      const int row = g >> 2, c = g & 3;
      U16* base_h = Bh + (p * 256 + w * 64) * 8;  // wave-uniform
      U16* base_l = Bl + (p * 256 + w * 64) * 8;
      gl_lds16(bh_src + row * 1024 + k0 + c * 8, base_h);
      gl_lds16(bl_src + row * 1024 + k0 + c * 8, base_l);
    }
    // reg-stage + split A tile [128 m][32 k] from fp32 x
    {
      const float* s = x + (m0 + arow) * 1024 + k0 + acol;
      float v[16];
#pragma unroll
      for (int i = 0; i < 16; i += 4) {
        float4 f = *(const float4*)(s + i);
        v[i] = f.x; v[i + 1] = f.y; v[i + 2] = f.z; v[i + 3] = f.w;
      }
      vbf8 h0, l0, h1, l1;
#pragma unroll
      for (int i = 0; i < 8; ++i) {
        U16 a = f2bf(v[i]);
        h0[i] = (short)a; l0[i] = (short)f2bf(v[i] - bf2f(a));
        U16 b = f2bf(v[8 + i]);
        h1[i] = (short)b; l1[i] = (short)f2bf(v[8 + i] - bf2f(b));
      }
      *(vbf8*)(Ah + arow * 32 + acol)     = h0;
      *(vbf8*)(Ah + arow * 32 + acol + 8) = h1;
      *(vbf8*)(Al + arow * 32 + acol)     = l0;
      *(vbf8*)(Al + arow * 32 + acol + 8) = l1;
    }
    __syncthreads();

    vbf8 a_h[4], a_l[4], b_h[4], b_l[4];
#pragma unroll
    for (int i = 0; i < 4; ++i) {
      a_h[i] = *(const vbf8*)(Ah + (wm + i * 16 + fr) * 32 + fq * 8);
      a_l[i] = *(const vbf8*)(Al + (wm + i * 16 + fr) * 32 + fq * 8);
      b_h[i] = *(const vbf8*)(Bh + (wn + i * 16 + fr) * 32 + fq * 8);
      b_l[i] = *(const vbf8*)(Bl + (wn + i * 16 + fr) * 32 + fq * 8);
    }
#pragma unroll
    for (int i = 0; i < 4; ++i)
#pragma unroll
      for (int j = 0; j < 4; ++j) {  // (Ah+Al)(Bh+Bl) dropping Al*Bl
        acc[i][j] = __builtin_amdgcn_mfma_f32_16x16x32_bf16(a_h[i], b_h[j], acc[i][j], 0, 0, 0);
        acc[i][j] = __builtin_amdgcn_mfma_f32_16x16x32_bf16(a_h[i], b_l[j], acc[i][j], 0, 0, 0);
        acc[i][j] = __builtin_amdgcn_mfma_f32_16x16x32_bf16(a_l[i], b_h[j], acc[i][j], 0, 0, 0);
      }
    __syncthreads();
  }

  if (nt < 2) {  // Q or K: split hi/lo, natural [m][128] layout
    U16* dh = (nt == 0) ? qh : kh;
    U16* dl = (nt == 0) ? ql : kl;
#pragma unroll
    for (int i = 0; i < 4; ++i)
#pragma unroll
      for (int j = 0; j < 4; ++j)
#pragma unroll
        for (int r = 0; r < 4; ++r) {
          const int row = m0 + wm + i * 16 + fq * 4 + r;  // C/D: row=(lane>>4)*4+r
          const int col = wn + j * 16 + fr;               //      col=lane&15
          const float val = acc[i][j][r];
          const U16 h = f2bf(val);
          dh[row * 128 + col] = h;
          dl[row * 128 + col] = f2bf(val - bf2f(h));
        }
  } else {  // V: transpose via LDS -> vt[b][d][t], coalesced writeout
    U16* tl = (U16*)smem;  // [128 d][136] (pad kills bank conflicts)
#pragma unroll
    for (int i = 0; i < 4; ++i)
#pragma unroll
      for (int j = 0; j < 4; ++j)
#pragma unroll
        for (int r = 0; r < 4; ++r) {
          const int ml = wm + i * 16 + fq * 4 + r;
          const int col = wn + j * 16 + fr;
          tl[col * 136 + ml] = f2bf(acc[i][j][r]);
        }
    __syncthreads();
    const int bb = m0 >> 11, t0 = m0 & 2047;
#pragma unroll
    for (int p = 0; p < 8; ++p) {
      const int g = p * 256 + tid;
      const int d = g >> 4, c = g & 15;
      *(vbf8*)(vt + (bb * 128 + d) * 2048 + t0 + c * 8) = *(const vbf8*)(tl + d * 136 + c * 8);
    }
  }
}

// ---------------- kernel 3: causal flash attention ----------------------------------
// QBLK=32 (wave-pairs split s-cols 0-31/32-63, merged at end), SBLK=64.
// grid 512 = 8 b * 64 q-tiles, ordered heavy-first/light-second so CU pairs balance.
__global__ __launch_bounds__(256) void flash_kernel(
    const U16* __restrict__ qh, const U16* __restrict__ ql, const U16* __restrict__ kh,
    const U16* __restrict__ kl, const U16* __restrict__ vt, float* __restrict__ out) {
  __shared__ __align__(16) char smem[54272];
  U16* Kh = (U16*)smem;             // [64 s][128 d], byte^((s&7)<<4) swizzled
  U16* Kl = (U16*)(smem + 16384);
  U16* Vt = (U16*)(smem + 32768);   // [128 d][64 s], byte^((d&7)<<4) swizzled
  U16* Pl = (U16*)(smem + 49152);   // [4 waves][16][40]

  const int tid = threadIdx.x;
  const int w = tid >> 6, lane = tid & 63;
  const int fr = lane & 15, fq = lane >> 4;
  const int bid = blockIdx.x;
  const int bb = bid & 7;           // batch -> XCD round-robin locality
  const int jj = bid >> 3;
  const int qt = (bid < 256) ? (63 - jj) : (jj - 32);  // desc then asc -> balanced pairs/CU
  const int q0 = qt * 32;
  const int pairI = w >> 1;         // s-column half
  const int wrow = (w & 1) * 16;    // q-row half of the 32-row tile

  // hoisted Q fragments (A-frag: row=lane&15, k=(lane>>4)*8)
  vbf8 q_h[4], q_l[4];
  {
    const int rg = (bb * 2048 + q0 + wrow + fr) * 128 + fq * 8;
#pragma unroll
    for (int kc = 0; kc < 4; ++kc) {
      q_h[kc] = *(const vbf8*)(qh + rg + kc * 32);
      q_l[kc] = *(const vbf8*)(ql + rg + kc * 32);
    }
  }

  const vf4 vzero = {0.f, 0.f, 0.f, 0.f};
  vf4 oacc[8];
#pragma unroll
  for (int i = 0; i < 8; ++i) oacc[i] = vzero;
  float m_r[4], l_r[4];
#pragma unroll
  for (int r = 0; r < 4; ++r) { m_r[r] = -__builtin_inff(); l_r[r] = 0.f; }

  const int nlast = (qt + 2) >> 1;  // # of 64-wide s-tiles covering s <= q0+31
  for (int ntile = 0; ntile < nlast; ++ntile) {
    const int s0 = ntile * 64;
    // stage K hi/lo + V^T with source-side XOR swizzle (both-sides rule)
#pragma unroll
    for (int p = 0; p < 4; ++p) {
      const int g = p * 256 + tid;
      U16* ldsb = (U16*)0;
      const int lb = (p * 256 + w * 64) * 8;  // wave-uniform granule base
      {
        const int s = g >> 4, c = g & 15;
        const int cl = c ^ (s & 7);
        const int src = (bb * 2048 + s0 + s) * 128 + cl * 8;
        gl_lds16(kh + src, Kh + lb);
        gl_lds16(kl + src, Kl + lb);
      }
      {
        const int d = g >> 3, c = g & 7;
        const int cv = c ^ (d & 7);
        gl_lds16(vt + (bb * 128 + d) * 2048 + s0 + cv * 8, Vt + lb);
      }
      (void)ldsb;
    }
    __syncthreads();

    // S = Q K^T (bf16x3): D row=q (fq*4+r), col=s (fr)
    vf4 sacc[2] = {vzero, vzero};
#pragma unroll
    for (int nf = 0; nf < 2; ++nf) {
      const int s_loc = pairI * 32 + nf * 16 + fr;
      const int swz = (s_loc & 7) << 4;
#pragma unroll
      for (int kc = 0; kc < 4; ++kc) {
        const int off = ((s_loc * 256 + kc * 64 + fq * 16) ^ swz) >> 1;
        vbf8 kfh = *(const vbf8*)(Kh + off);
        vbf8 kfl = *(const vbf8*)(Kl + off);
        sacc[nf] = __builtin_amdgcn_mfma_f32_16x16x32_bf16(q_h[kc], kfh, sacc[nf], 0, 0, 0);
        sacc[nf] = __builtin_amdgcn_mfma_f32_16x16x32_bf16(q_h[kc], kfl, sacc[nf], 0, 0, 0);
        sacc[nf] = __builtin_amdgcn_mfma_f32_16x16x32_bf16(q_l[kc], kfh, sacc[nf], 0, 0, 0);
      }
    }

    if (ntile == nlast - 1) {  // causal mask only ever needed on the last tile
#pragma unroll
      for (int nf = 0; nf < 2; ++nf) {
        const int s_g = s0 + pairI * 32 + nf * 16 + fr;
#pragma unroll
        for (int r = 0; r < 4; ++r) {
          const int q_g = q0 + wrow + fq * 4 + r;
          if (s_g > q_g) sacc[nf][r] = -__builtin_inff();
        }
      }
    }

    // online softmax; row-group = 16 consecutive lanes (same fq)
    float tmax[4];
#pragma unroll
    for (int r = 0; r < 4; ++r) tmax[r] = fmaxf(sacc[0][r], sacc[1][r]);
#pragma unroll
    for (int off = 1; off < 16; off <<= 1)
#pragma unroll
      for (int r = 0; r < 4; ++r) tmax[r] = fmaxf(tmax[r], __shfl_xor(tmax[r], off, 64));

    float alpha[4], mne[4];
#pragma unroll
    for (int r = 0; r < 4; ++r) {
      const float mn = fmaxf(m_r[r], tmax[r]);
      mne[r] = (mn == -__builtin_inff()) ? 0.f : mn;  // all-masked guard (no -inf - -inf NaN)
      alpha[r] = __expf(m_r[r] - mne[r]);
      m_r[r] = mn;
    }

    float psum[4] = {0.f, 0.f, 0.f, 0.f};
    U16 pb[2][4];
#pragma unroll
    for (int nf = 0; nf < 2; ++nf)
#pragma unroll
      for (int r = 0; r < 4; ++r) {
        const float pv = __expf(sacc[nf][r] - mne[r]);
        psum[r] += pv;
        pb[nf][r] = f2bf(pv);
      }
#pragma unroll
    for (int off = 1; off < 16; off <<= 1)
#pragma unroll
      for (int r = 0; r < 4; ++r) psum[r] += __shfl_xor(psum[r], off, 64);
#pragma unroll
    for (int r = 0; r < 4; ++r) l_r[r] = l_r[r] * alpha[r] + psum[r];
#pragma unroll
    for (int i = 0; i < 8; ++i)
#pragma unroll
      for (int r = 0; r < 4; ++r) oacc[i][r] *= alpha[r];

    // P (C-layout) -> LDS -> A-frag relayout; wave-local, lgkmcnt fence suffices
    U16* pw = Pl + w * (16 * 40);
#pragma unroll
    for (int nf = 0; nf < 2; ++nf)
#pragma unroll
      for (int r = 0; r < 4; ++r) pw[(fq * 4 + r) * 40 + nf * 16 + fr] = pb[nf][r];
    asm volatile("s_waitcnt lgkmcnt(0)" ::: "memory");
    const vbf8 pf = *(const vbf8*)(pw + fr * 40 + fq * 8);
#pragma unroll
    for (int i = 0; i < 8; ++i) {
      const int d_loc = i * 16 + fr;
      const int off = ((d_loc * 128 + (pairI * 32 + fq * 8) * 2) ^ ((d_loc & 7) << 4)) >> 1;
      const vbf8 vfr = *(const vbf8*)(Vt + off);
      oacc[i] = __builtin_amdgcn_mfma_f32_16x16x32_bf16(pf, vfr, oacc[i], 0, 0, 0);
    }
    __syncthreads();
  }

  // merge the two s-column halves (pair1 -> LDS, pair0 combines + writes out)
  float* O_l = (float*)smem;                  // [32][128]
  float* m_l = (float*)(smem + 16384);
  float* l_l = (float*)(smem + 16384 + 256);
  if (pairI == 1) {
#pragma unroll
    for (int i = 0; i < 8; ++i)
#pragma unroll
      for (int r = 0; r < 4; ++r)
        O_l[(wrow + fq * 4 + r) * 128 + i * 16 + fr] = oacc[i][r];
    if (fr == 0) {
#pragma unroll
      for (int r = 0; r < 4; ++r) {
        m_l[wrow + fq * 4 + r] = m_r[r];
        l_l[wrow + fq * 4 + r] = l_r[r];
      }
    }
  }
  __syncthreads();
  if (pairI == 0) {
    float aA[4], aB[4], inv[4];
#pragma unroll
    for (int r = 0; r < 4; ++r) {
      const int row = wrow + fq * 4 + r;
      const float mB = m_l[row], lB = l_l[row];
      const float M = fmaxf(m_r[r], mB);      // pair0 max is always finite
      aA[r] = __expf(m_r[r] - M);
      aB[r] = __expf(mB - M);
      inv[r] = 1.f / (l_r[r] * aA[r] + lB * aB[r]);
    }
#pragma unroll
    for (int i = 0; i < 8; ++i)
#pragma unroll
      for (int r = 0; r < 4; ++r) {
        const int row = wrow + fq * 4 + r;
        out[(bb * 2048 + q0 + row) * 128 + i * 16 + fr] =
            (oacc[i][r] * aA[r] + O_l[row * 128 + i * 16 + fr] * aB[r]) * inv[r];
      }
  }
}

// ---------------- host ----------------------------------------------------------------
extern "C" void kernel_launch(void* const* d_in, const int* in_sizes, int n_in, void* d_out,
                              int out_size, void* d_ws, size_t ws_size, hipStream_t stream) {
  const float* x = (const float*)d_in[0];
  const float* wq = (const float*)d_in[1];
  const float* wk = (const float*)d_in[2];
  const float* wv = (const float*)d_in[3];
  char* ws = (char*)d_ws;
  // ws layout (bytes): total ~21.5 MB
  U16* wth = (U16*)(ws);              // 786432
  U16* wtl = (U16*)(ws + 786432);     // 786432
  U16* qh  = (U16*)(ws + 1572864);    // 4 MiB each below
  U16* ql  = (U16*)(ws + 5767168);
  U16* kh  = (U16*)(ws + 9961472);
  U16* kl  = (U16*)(ws + 14155776);
  U16* vt  = (U16*)(ws + 18350080);   // [8][128][2048] bf16
  float* out = (float*)d_out;

  wsplit_kernel<<<dim3(1536), dim3(256), 0, stream>>>(wq, wk, wv, wth, wtl);
  qkv_kernel<<<dim3(128, 3), dim3(256), 0, stream>>>(x, wth, wtl, qh, ql, kh, kl, vt);
  flash_kernel<<<dim3(512), dim3(256), 0, stream>>>(qh, ql, kh, kl, vt, out);
}

// Round 3
// 114.336 us; speedup vs baseline: 1.1358x; 1.1358x over previous
//
#include <hip/hip_runtime.h>

// Head: x[8,2048,1024] fp32 -> q,k,v = x@w{q,k,v} -> causal softmax(q k^T * sqrt(128)) @ v
// Precision: bf16x3 split-GEMM for Q/K projections and QK^T (fp32-grade scores), bf16 V/PV.

#define NB 8
#define NT 2048
#define NE 1024
#define ND 128
#define NM (NB * NT)  // 16384

typedef unsigned short U16;
typedef unsigned int U32;
typedef __attribute__((ext_vector_type(8))) short vbf8;  // 8 bf16 (4 VGPR) MFMA frag
typedef __attribute__((ext_vector_type(4))) float vf4;   // MFMA 16x16 accum

__device__ __forceinline__ U16 f2bf(float f) {  // RNE fp32->bf16
  U32 u = __builtin_bit_cast(U32, f);
  u += 0x7fffu + ((u >> 16) & 1u);
  return (U16)(u >> 16);
}
__device__ __forceinline__ float bf2f(U16 h) {
  U32 u = ((U32)h) << 16;
  return __builtin_bit_cast(float, u);
}
__device__ __forceinline__ void gl_lds16(const void* g, void* l) {
  // async global->LDS, 16B per lane; LDS dest = wave-uniform base + lane*16
  __builtin_amdgcn_global_load_lds((__attribute__((address_space(1))) void*)g,
                                   (__attribute__((address_space(3))) void*)l, 16, 0, 0);
}

// ---------------- kernel 1: weight transpose + split (fold sqrt(128) into wq) ---------
__global__ void wsplit_kernel(const float* __restrict__ wq, const float* __restrict__ wk,
                              const float* __restrict__ wv, U16* __restrict__ wth,
                              U16* __restrict__ wtl) {
  int id = blockIdx.x * 256 + threadIdx.x;  // [0, 384*1024)
  if (id >= 384 * 1024) return;
  int n = id >> 10, e = id & 1023;
  float v;
  if (n < 128)      v = wq[e * 128 + n] * 11.313708498984761f;  // scores * d^0.5 folded in
  else if (n < 256) v = wk[e * 128 + (n - 128)];
  else              v = wv[e * 128 + (n - 256)];
  U16 h = f2bf(v);
  wth[id] = h;
  wtl[id] = f2bf(v - bf2f(h));
}

// ---------------- kernel 2: QKV projection, bf16x3 split GEMM ------------------------
// Tile 64(M)x128(N), BK=64. grid (256, 3): y 0->Q(hi/lo) 1->K(hi/lo) 2->V(bf16, vt).
// LDS layout [row][8 granules of 16B], granule XOR-swizzled by (row&7) on BOTH sides.
__global__ __launch_bounds__(256, 3) void qkv_kernel(
    const float* __restrict__ x, const U16* __restrict__ wth, const U16* __restrict__ wtl,
    U16* __restrict__ qh, U16* __restrict__ ql, U16* __restrict__ kh, U16* __restrict__ kl,
    U16* __restrict__ vt) {
  __shared__ __align__(16) char smem[49152];  // Ah/Al 8KB each, Bh/Bl 16KB each
  char* Ah = smem;
  char* Al = smem + 8192;
  char* Bh = smem + 16384;
  char* Bl = smem + 32768;

  const int tid = threadIdx.x;
  const int w = tid >> 6, lane = tid & 63;
  const int fr = lane & 15, fq = lane >> 4;
  const int m0 = blockIdx.x * 64;
  const int nt = blockIdx.y;
  const U16* bh_src = wth + nt * (128 * 1024);
  const U16* bl_src = wtl + nt * (128 * 1024);

  const vf4 vzero = {0.f, 0.f, 0.f, 0.f};
  vf4 acc[2][4];
#pragma unroll
  for (int i = 0; i < 2; ++i)
#pragma unroll
    for (int j = 0; j < 4; ++j) acc[i][j] = vzero;

  const int wm = (w >> 1) * 32, wn = (w & 1) * 64;  // wave tile 32x64
  const int arow = tid >> 2, ag = tid & 3;          // A stage: 2 granules (ag, ag+4)

  for (int k0 = 0; k0 < 1024; k0 += 64) {
    // --- async-stage B hi(/lo) [128 n][64 k], source-granule pre-swizzled ---
#pragma unroll
    for (int p = 0; p < 4; ++p) {
      const int g = p * 256 + tid;
      const int row = g >> 3, c = g & 7;
      const int sc = c ^ (row & 7);
      const int ldsb = (p * 256 + w * 64) * 16;  // wave-uniform granule base
      gl_lds16(bh_src + row * 1024 + k0 + sc * 8, Bh + ldsb);
      if (nt < 2) gl_lds16(bl_src + row * 1024 + k0 + sc * 8, Bl + ldsb);
    }
    // --- reg-stage + split A [64 m][64 k] from fp32 x, swizzled VALU stores ---
    {
      const float* s = x + (size_t)(m0 + arow) * 1024 + k0 + ag * 8;
      float v0[8], v1[8];
      ((float4*)v0)[0] = *(const float4*)(s);
      ((float4*)v0)[1] = *(const float4*)(s + 4);
      ((float4*)v1)[0] = *(const float4*)(s + 32);
      ((float4*)v1)[1] = *(const float4*)(s + 36);
      vbf8 h0, l0, h1, l1;
#pragma unroll
      for (int i = 0; i < 8; ++i) {
        U16 a = f2bf(v0[i]);
        h0[i] = (short)a; l0[i] = (short)f2bf(v0[i] - bf2f(a));
        U16 b = f2bf(v1[i]);
        h1[i] = (short)b; l1[i] = (short)f2bf(v1[i] - bf2f(b));
      }
      const int sw = arow & 7;
      *(vbf8*)(Ah + arow * 128 + ((ag ^ sw) << 4))       = h0;
      *(vbf8*)(Ah + arow * 128 + (((ag + 4) ^ sw) << 4)) = h1;
      if (nt < 2) {
        *(vbf8*)(Al + arow * 128 + ((ag ^ sw) << 4))       = l0;
        *(vbf8*)(Al + arow * 128 + (((ag + 4) ^ sw) << 4)) = l1;
      }
    }
    __syncthreads();

    if (nt < 2) {
#pragma unroll
      for (int kc = 0; kc < 2; ++kc) {
        vbf8 a_h[2], a_l[2], b_h[4], b_l[4];
#pragma unroll
        for (int i = 0; i < 2; ++i) {
          const int row = wm + i * 16 + fr;
          const int off = row * 128 + (((kc * 4 + fq) ^ (row & 7)) << 4);
          a_h[i] = *(const vbf8*)(Ah + off);
          a_l[i] = *(const vbf8*)(Al + off);
        }
#pragma unroll
        for (int j = 0; j < 4; ++j) {
          const int row = wn + j * 16 + fr;
          const int off = row * 128 + (((kc * 4 + fq) ^ (row & 7)) << 4);
          b_h[j] = *(const vbf8*)(Bh + off);
          b_l[j] = *(const vbf8*)(Bl + off);
        }
#pragma unroll
        for (int i = 0; i < 2; ++i)
#pragma unroll
          for (int j = 0; j < 4; ++j) {  // (Ah+Al)(Bh+Bl) dropping Al*Bl
            acc[i][j] = __builtin_amdgcn_mfma_f32_16x16x32_bf16(a_h[i], b_h[j], acc[i][j], 0, 0, 0);
            acc[i][j] = __builtin_amdgcn_mfma_f32_16x16x32_bf16(a_h[i], b_l[j], acc[i][j], 0, 0, 0);
            acc[i][j] = __builtin_amdgcn_mfma_f32_16x16x32_bf16(a_l[i], b_h[j], acc[i][j], 0, 0, 0);
          }
      }
    } else {  // V: hh only
#pragma unroll
      for (int kc = 0; kc < 2; ++kc) {
        vbf8 a_h[2], b_h[4];
#pragma unroll
        for (int i = 0; i < 2; ++i) {
          const int row = wm + i * 16 + fr;
          a_h[i] = *(const vbf8*)(Ah + row * 128 + (((kc * 4 + fq) ^ (row & 7)) << 4));
        }
#pragma unroll
        for (int j = 0; j < 4; ++j) {
          const int row = wn + j * 16 + fr;
          b_h[j] = *(const vbf8*)(Bh + row * 128 + (((kc * 4 + fq) ^ (row & 7)) << 4));
        }
#pragma unroll
        for (int i = 0; i < 2; ++i)
#pragma unroll
          for (int j = 0; j < 4; ++j)
            acc[i][j] = __builtin_amdgcn_mfma_f32_16x16x32_bf16(a_h[i], b_h[j], acc[i][j], 0, 0, 0);
      }
    }
    __syncthreads();
  }

  if (nt < 2) {  // Q or K: split hi/lo, natural [m][128] layout
    U16* dh = (nt == 0) ? qh : kh;
    U16* dl = (nt == 0) ? ql : kl;
#pragma unroll
    for (int i = 0; i < 2; ++i)
#pragma unroll
      for (int j = 0; j < 4; ++j)
#pragma unroll
        for (int r = 0; r < 4; ++r) {
          const int row = m0 + wm + i * 16 + fq * 4 + r;  // C/D: row=(lane>>4)*4+r
          const int col = wn + j * 16 + fr;               //      col=lane&15
          const float val = acc[i][j][r];
          const U16 h = f2bf(val);
          dh[row * 128 + col] = h;
          dl[row * 128 + col] = f2bf(val - bf2f(h));
        }
  } else {  // V: transpose via LDS -> vt[b][d][t], coalesced writeout
    U16* tl = (U16*)smem;  // [128 d][80] (pad kills conflicts; 20480 B < 48 KB)
#pragma unroll
    for (int i = 0; i < 2; ++i)
#pragma unroll
      for (int j = 0; j < 4; ++j)
#pragma unroll
        for (int r = 0; r < 4; ++r) {
          const int ml = wm + i * 16 + fq * 4 + r;
          const int col = wn + j * 16 + fr;
          tl[col * 80 + ml] = f2bf(acc[i][j][r]);
        }
    __syncthreads();
    const int bb = m0 >> 11, t0 = m0 & 2047;
#pragma unroll
    for (int p = 0; p < 4; ++p) {
      const int g = p * 256 + tid;
      const int d = g >> 3, c = g & 7;
      *(vbf8*)(vt + (size_t)(bb * 128 + d) * 2048 + t0 + c * 8) = *(const vbf8*)(tl + d * 80 + c * 8);
    }
  }
}

// ---------------- kernel 3: causal flash attention ----------------------------------
// QBLK=32 (wave-pairs split s-cols 0-31/32-63, merged at end), SBLK=64.
// grid 512 = 8 b * 64 q-tiles, ordered heavy-first/light-second so CU pairs balance.
__global__ __launch_bounds__(256) void flash_kernel(
    const U16* __restrict__ qh, const U16* __restrict__ ql, const U16* __restrict__ kh,
    const U16* __restrict__ kl, const U16* __restrict__ vt, float* __restrict__ out) {
  __shared__ __align__(16) char smem[54272];
  U16* Kh = (U16*)smem;             // [64 s][128 d], byte^((s&7)<<4) swizzled
  U16* Kl = (U16*)(smem + 16384);
  U16* Vt = (U16*)(smem + 32768);   // [128 d][64 s], byte^((d&7)<<4) swizzled
  U16* Pl = (U16*)(smem + 49152);   // [4 waves][16][40]

  const int tid = threadIdx.x;
  const int w = tid >> 6, lane = tid & 63;
  const int fr = lane & 15, fq = lane >> 4;
  const int bid = blockIdx.x;
  const int bb = bid & 7;           // batch -> XCD round-robin locality
  const int jj = bid >> 3;
  const int qt = (bid < 256) ? (63 - jj) : (jj - 32);  // desc then asc -> balanced pairs/CU
  const int q0 = qt * 32;
  const int pairI = w >> 1;         // s-column half
  const int wrow = (w & 1) * 16;    // q-row half of the 32-row tile

  // hoisted Q fragments (A-frag: row=lane&15, k=(lane>>4)*8)
  vbf8 q_h[4], q_l[4];
  {
    const int rg = (bb * 2048 + q0 + wrow + fr) * 128 + fq * 8;
#pragma unroll
    for (int kc = 0; kc < 4; ++kc) {
      q_h[kc] = *(const vbf8*)(qh + rg + kc * 32);
      q_l[kc] = *(const vbf8*)(ql + rg + kc * 32);
    }
  }

  const vf4 vzero = {0.f, 0.f, 0.f, 0.f};
  vf4 oacc[8];
#pragma unroll
  for (int i = 0; i < 8; ++i) oacc[i] = vzero;
  float m_r[4], l_r[4];
#pragma unroll
  for (int r = 0; r < 4; ++r) { m_r[r] = -__builtin_inff(); l_r[r] = 0.f; }

  const int nlast = (qt + 2) >> 1;  // # of 64-wide s-tiles covering s <= q0+31
  for (int ntile = 0; ntile < nlast; ++ntile) {
    const int s0 = ntile * 64;
    // stage K hi/lo + V^T with source-side XOR swizzle (both-sides rule)
#pragma unroll
    for (int p = 0; p < 4; ++p) {
      const int g = p * 256 + tid;
      const int lb = (p * 256 + w * 64) * 8;  // wave-uniform granule base
      {
        const int s = g >> 4, c = g & 15;
        const int cl = c ^ (s & 7);
        const int src = (bb * 2048 + s0 + s) * 128 + cl * 8;
        gl_lds16(kh + src, Kh + lb);
        gl_lds16(kl + src, Kl + lb);
      }
      {
        const int d = g >> 3, c = g & 7;
        const int cv = c ^ (d & 7);
        gl_lds16(vt + (bb * 128 + d) * 2048 + s0 + cv * 8, Vt + lb);
      }
    }
    __syncthreads();

    // S = Q K^T (bf16x3): D row=q (fq*4+r), col=s (fr)
    vf4 sacc[2] = {vzero, vzero};
    __builtin_amdgcn_s_setprio(1);
#pragma unroll
    for (int nf = 0; nf < 2; ++nf) {
      const int s_loc = pairI * 32 + nf * 16 + fr;
      const int swz = (s_loc & 7) << 4;
#pragma unroll
      for (int kc = 0; kc < 4; ++kc) {
        const int off = ((s_loc * 256 + kc * 64 + fq * 16) ^ swz) >> 1;
        vbf8 kfh = *(const vbf8*)(Kh + off);
        vbf8 kfl = *(const vbf8*)(Kl + off);
        sacc[nf] = __builtin_amdgcn_mfma_f32_16x16x32_bf16(q_h[kc], kfh, sacc[nf], 0, 0, 0);
        sacc[nf] = __builtin_amdgcn_mfma_f32_16x16x32_bf16(q_h[kc], kfl, sacc[nf], 0, 0, 0);
        sacc[nf] = __builtin_amdgcn_mfma_f32_16x16x32_bf16(q_l[kc], kfh, sacc[nf], 0, 0, 0);
      }
    }
    __builtin_amdgcn_s_setprio(0);

    if (ntile == nlast - 1) {  // causal mask only ever needed on the last tile
#pragma unroll
      for (int nf = 0; nf < 2; ++nf) {
        const int s_g = s0 + pairI * 32 + nf * 16 + fr;
#pragma unroll
        for (int r = 0; r < 4; ++r) {
          const int q_g = q0 + wrow + fq * 4 + r;
          if (s_g > q_g) sacc[nf][r] = -__builtin_inff();
        }
      }
    }

    // online softmax; row-group = 16 consecutive lanes (same fq)
    float tmax[4];
#pragma unroll
    for (int r = 0; r < 4; ++r) tmax[r] = fmaxf(sacc[0][r], sacc[1][r]);
#pragma unroll
    for (int off = 1; off < 16; off <<= 1)
#pragma unroll
      for (int r = 0; r < 4; ++r) tmax[r] = fmaxf(tmax[r], __shfl_xor(tmax[r], off, 64));

    float alpha[4], mne[4];
#pragma unroll
    for (int r = 0; r < 4; ++r) {
      const float mn = fmaxf(m_r[r], tmax[r]);
      mne[r] = (mn == -__builtin_inff()) ? 0.f : mn;  // all-masked guard (no -inf - -inf NaN)
      alpha[r] = __expf(m_r[r] - mne[r]);
      m_r[r] = mn;
    }

    float psum[4] = {0.f, 0.f, 0.f, 0.f};
    U16 pb[2][4];
#pragma unroll
    for (int nf = 0; nf < 2; ++nf)
#pragma unroll
      for (int r = 0; r < 4; ++r) {
        const float pv = __expf(sacc[nf][r] - mne[r]);
        psum[r] += pv;
        pb[nf][r] = f2bf(pv);
      }
#pragma unroll
    for (int off = 1; off < 16; off <<= 1)
#pragma unroll
      for (int r = 0; r < 4; ++r) psum[r] += __shfl_xor(psum[r], off, 64);
#pragma unroll
    for (int r = 0; r < 4; ++r) l_r[r] = l_r[r] * alpha[r] + psum[r];
#pragma unroll
    for (int i = 0; i < 8; ++i)
#pragma unroll
      for (int r = 0; r < 4; ++r) oacc[i][r] *= alpha[r];

    // P (C-layout) -> LDS -> A-frag relayout; wave-local, lgkmcnt fence suffices
    U16* pw = Pl + w * (16 * 40);
#pragma unroll
    for (int nf = 0; nf < 2; ++nf)
#pragma unroll
      for (int r = 0; r < 4; ++r) pw[(fq * 4 + r) * 40 + nf * 16 + fr] = pb[nf][r];
    asm volatile("s_waitcnt lgkmcnt(0)" ::: "memory");
    const vbf8 pf = *(const vbf8*)(pw + fr * 40 + fq * 8);
    __builtin_amdgcn_s_setprio(1);
#pragma unroll
    for (int i = 0; i < 8; ++i) {
      const int d_loc = i * 16 + fr;
      const int off = ((d_loc * 128 + (pairI * 32 + fq * 8) * 2) ^ ((d_loc & 7) << 4)) >> 1;
      const vbf8 vfr = *(const vbf8*)(Vt + off);
      oacc[i] = __builtin_amdgcn_mfma_f32_16x16x32_bf16(pf, vfr, oacc[i], 0, 0, 0);
    }
    __builtin_amdgcn_s_setprio(0);
    __syncthreads();
  }

  // merge the two s-column halves (pair1 -> LDS, pair0 combines + writes out)
  float* O_l = (float*)smem;                  // [32][128]
  float* m_l = (float*)(smem + 16384);
  float* l_l = (float*)(smem + 16384 + 256);
  if (pairI == 1) {
#pragma unroll
    for (int i = 0; i < 8; ++i)
#pragma unroll
      for (int r = 0; r < 4; ++r)
        O_l[(wrow + fq * 4 + r) * 128 + i * 16 + fr] = oacc[i][r];
    if (fr == 0) {
#pragma unroll
      for (int r = 0; r < 4; ++r) {
        m_l[wrow + fq * 4 + r] = m_r[r];
        l_l[wrow + fq * 4 + r] = l_r[r];
      }
    }
  }
  __syncthreads();
  if (pairI == 0) {
    float aA[4], aB[4], inv[4];
#pragma unroll
    for (int r = 0; r < 4; ++r) {
      const int row = wrow + fq * 4 + r;
      const float mB = m_l[row], lB = l_l[row];
      const float M = fmaxf(m_r[r], mB);      // pair0 max is always finite
      aA[r] = __expf(m_r[r] - M);
      aB[r] = __expf(mB - M);
      inv[r] = 1.f / (l_r[r] * aA[r] + lB * aB[r]);
    }
#pragma unroll
    for (int i = 0; i < 8; ++i)
#pragma unroll
      for (int r = 0; r < 4; ++r) {
        const int row = wrow + fq * 4 + r;
        out[(bb * 2048 + q0 + row) * 128 + i * 16 + fr] =
            (oacc[i][r] * aA[r] + O_l[row * 128 + i * 16 + fr] * aB[r]) * inv[r];
      }
  }
}

// ---------------- host ----------------------------------------------------------------
extern "C" void kernel_launch(void* const* d_in, const int* in_sizes, int n_in, void* d_out,
                              int out_size, void* d_ws, size_t ws_size, hipStream_t stream) {
  const float* x = (const float*)d_in[0];
  const float* wq = (const float*)d_in[1];
  const float* wk = (const float*)d_in[2];
  const float* wv = (const float*)d_in[3];
  char* ws = (char*)d_ws;
  // ws layout (bytes): total ~21.5 MB
  U16* wth = (U16*)(ws);              // 786432
  U16* wtl = (U16*)(ws + 786432);     // 786432
  U16* qh  = (U16*)(ws + 1572864);    // 4 MiB each below
  U16* ql  = (U16*)(ws + 5767168);
  U16* kh  = (U16*)(ws + 9961472);
  U16* kl  = (U16*)(ws + 14155776);
  U16* vt  = (U16*)(ws + 18350080);   // [8][128][2048] bf16
  float* out = (float*)d_out;

  wsplit_kernel<<<dim3(1536), dim3(256), 0, stream>>>(wq, wk, wv, wth, wtl);
  qkv_kernel<<<dim3(256, 3), dim3(256), 0, stream>>>(x, wth, wtl, qh, ql, kh, kl, vt);
  flash_kernel<<<dim3(512), dim3(256), 0, stream>>>(qh, ql, kh, kl, vt, out);
}